// Round 15
// baseline (163.098 us; speedup 1.0000x reference)
//
#include <hip/hip_runtime.h>
#include <hip/hip_bf16.h>

#define C 32
#define R 8
#define NPB 32        // nodes per block in nodeZ part
#define K_ELL 32      // ELL slots per row
#define OVF_CAP 65536

typedef unsigned int u32;
typedef unsigned short u16;
__device__ __forceinline__ float bflo(u32 u) { return __uint_as_float(u << 16); }
__device__ __forceinline__ float bfhi(u32 u) { return __uint_as_float(u & 0xffff0000u); }

// ---- M[r][c][j] = sum_o W_tp[c][r][o] * W1[r*C+o][j]   (f32, 32 KB) ----
__global__ void k_prepM(const float* __restrict__ Wtp, const float* __restrict__ W1,
                        float* __restrict__ M) {
    int idx = blockIdx.x * 256 + threadIdx.x;
    if (idx >= R * C * C) return;
    int r = idx >> 10;
    int c = (idx >> 5) & 31;
    int j = idx & 31;
    float acc = 0.f;
#pragma unroll
    for (int o = 0; o < C; ++o)
        acc = fmaf(Wtp[c * R * C + r * C + o], W1[(r * C + o) * C + j], acc);
    M[idx] = acc;
}

// ---- fused, 3 block ranges ----
// [0,PB):        pos4[n] = {pos[n,0..2], 0}   (16B-aligned copy for edge kernel)
// [PB,PB+ZB):    nodeZ: z[n][j][r] = sum_c x[n][c]*M[r][c][j]  (bf16, r contig)
// [PB+ZB,...):   scatter-lite: ell[row*32+local] = u16 col; overflow {row,col}
__global__ void k_fused(const float* __restrict__ x, const float* __restrict__ M,
                        __hip_bfloat16* __restrict__ z,
                        const int* __restrict__ ei, const float* __restrict__ pos,
                        float4* __restrict__ pos4,
                        int* __restrict__ cnt, int* __restrict__ ovfcnt,
                        uint2* __restrict__ ovf,
                        u16* __restrict__ ell, int N, int E, int PB, int ZB) {
    __shared__ float xs[NPB * C];
    int t = threadIdx.x;
    int bid = blockIdx.x;
    if (bid < PB) {
        int n = bid * 256 + t;
        if (n < N) {
            float4 p;
            p.x = pos[n * 3 + 0];
            p.y = pos[n * 3 + 1];
            p.z = pos[n * 3 + 2];
            p.w = 0.f;
            pos4[n] = p;
        }
    } else if (bid < PB + ZB) {
        int n0 = (bid - PB) * NPB;
        for (int i = t * 4; i < NPB * C; i += 256 * 4) {
            size_t gbase = (size_t)n0 * C + i;
            float4 v = make_float4(0.f, 0.f, 0.f, 0.f);
            if (gbase + 3 < (size_t)N * C) v = *(const float4*)(x + gbase);
            *(float4*)(xs + i) = v;
        }
        __syncthreads();
        int r = t & 7, j = t >> 3;
        float m[C];
#pragma unroll
        for (int c = 0; c < C; ++c) m[c] = M[r * C * C + c * C + j];
        int nmax = N - n0; if (nmax > NPB) nmax = NPB;
        for (int nn = 0; nn < nmax; ++nn) {
            const float* xp = xs + nn * C;
            float acc = 0.f;
#pragma unroll
            for (int c = 0; c < C; ++c) acc = fmaf(xp[c], m[c], acc);
            z[(size_t)(n0 + nn) * (R * C) + t] = __float2bfloat16(acc);
        }
    } else {
        int i = (bid - PB - ZB) * 256 + t;
        if (i < E) {
            int r = ei[i];
            int c = ei[E + i];
            r = ((unsigned)r < (unsigned)N) ? r : 0;
            c = ((unsigned)c < (unsigned)N) ? c : 0;
            int local = atomicAdd(&cnt[r], 1);
            if (local < K_ELL) {
                ell[(size_t)r * K_ELL + local] = (u16)c;
            } else {
                int q = atomicAdd(ovfcnt, 1);
                if (q < OVF_CAP) ovf[q] = make_uint2((u32)r, (u32)c);
            }
        }
    }
}

__device__ __forceinline__ float silu_f(float h) {
    return h * __builtin_amdgcn_rcpf(1.f + __expf(-h));
}

// per-lane full-rbf dot: h = b1j + sum_r rbf(d,r)*z_r  — 2 exps, no shuffles.
// rbf[r] = s*exp(-0.5(u-r)^2), u=d/w, w=5/7:  f_{r+1}=f_r*m_r, m_0=exp(u-1/2),
// m_{r+1}=m_r*e^-1.
__device__ __forceinline__ float rbf_dot(float d, uint4 zv, float b1j) {
    const float Einv = 0.36787944f;   // e^-1
    float u = 1.3999999f * d;
    float f = 0.3989423f * __expf(-0.5f * u * u);
    float t = __expf(u - 0.5f);
    float h = fmaf(f, bflo(zv.x), b1j);
    f *= t;            h = fmaf(f, bfhi(zv.x), h);
    t *= Einv; f *= t; h = fmaf(f, bflo(zv.y), h);
    t *= Einv; f *= t; h = fmaf(f, bfhi(zv.y), h);
    t *= Einv; f *= t; h = fmaf(f, bflo(zv.z), h);
    t *= Einv; f *= t; h = fmaf(f, bfhi(zv.z), h);
    t *= Einv; f *= t; h = fmaf(f, bflo(zv.w), h);
    t *= Einv; f *= t; h = fmaf(f, bfhi(zv.w), h);
    return h;
}

__device__ __forceinline__ float dist_f(float4 a, float4 b) {
    float dx = a.x - b.x, dy = a.y - b.y, dz = a.z - b.z;
    return sqrtf(fmaf(dx, dx, fmaf(dy, dy, dz * dz)) + 1e-12f);
}

// ---- per-row ELL edge kernel: 32 lanes = one row; fused W2/b2 epilogue ----
__global__ void k_edge_ell(const int* __restrict__ cnt, const u16* __restrict__ ell,
                           const __hip_bfloat16* __restrict__ z,
                           const float4* __restrict__ pos4,
                           const float* __restrict__ x, const float* __restrict__ b1,
                           const float* __restrict__ W2, const float* __restrict__ b2,
                           float* __restrict__ out, int N) {
    __shared__ float W2s[C * C];
    for (int i = threadIdx.x; i < C * C; i += blockDim.x) W2s[i] = W2[i];
    __syncthreads();
    int gt = blockIdx.x * blockDim.x + threadIdx.x;
    int j = gt & 31;
    int n = gt >> 5;
    if (n >= N) return;
    int deg = cnt[n];
    int m = deg < K_ELL ? deg : K_ELL;
    int mycol = (j < m) ? (int)ell[(size_t)n * K_ELL + j] : 0;
    float4 pr = pos4[n];
    float b1j = b1[j];
    float acc = 0.f;
    int base = 0;
    for (; base + 4 <= m; base += 4) {
        int c0 = __shfl(mycol, base + 0, 32);
        int c1 = __shfl(mycol, base + 1, 32);
        int c2 = __shfl(mycol, base + 2, 32);
        int c3 = __shfl(mycol, base + 3, 32);
        float4 q0 = pos4[c0];
        float4 q1 = pos4[c1];
        float4 q2 = pos4[c2];
        float4 q3 = pos4[c3];
        uint4 z0 = ((const uint4*)(z + (size_t)c0 * (R * C)))[j];
        uint4 z1 = ((const uint4*)(z + (size_t)c1 * (R * C)))[j];
        uint4 z2 = ((const uint4*)(z + (size_t)c2 * (R * C)))[j];
        uint4 z3 = ((const uint4*)(z + (size_t)c3 * (R * C)))[j];
        float h0 = rbf_dot(dist_f(pr, q0), z0, b1j);
        float h1 = rbf_dot(dist_f(pr, q1), z1, b1j);
        float h2 = rbf_dot(dist_f(pr, q2), z2, b1j);
        float h3 = rbf_dot(dist_f(pr, q3), z3, b1j);
        acc += silu_f(h0) + silu_f(h1) + silu_f(h2) + silu_f(h3);
    }
    for (; base < m; ++base) {
        int c0 = __shfl(mycol, base, 32);
        float4 q0 = pos4[c0];
        uint4 z0 = ((const uint4*)(z + (size_t)c0 * (R * C)))[j];
        acc += silu_f(rbf_dot(dist_f(pr, q0), z0, b1j));
    }
    // out[n][j] = x[n][j] + sum_i acc_i*W2[i][j] + deg*b2[j]   (deg = TRUE degree)
    float v = fmaf((float)deg, b2[j], x[(size_t)n * C + j]);
#pragma unroll
    for (int i = 0; i < C; ++i)
        v = fmaf(__shfl(acc, i, 32), W2s[i * C + j], v);
    out[(size_t)n * C + j] = v;
}

// ---- overflow fix-up: add W2-weighted silu of overflow edges (b2 already counted) ----
__global__ void k_overflow(const int* __restrict__ ovfcnt, const uint2* __restrict__ ovf,
                           const __hip_bfloat16* __restrict__ z,
                           const float4* __restrict__ pos4,
                           const float* __restrict__ b1, const float* __restrict__ W2,
                           float* __restrict__ out, int N) {
    int novf = ovfcnt[0];
    if (novf > OVF_CAP) novf = OVF_CAP;
    int gt = blockIdx.x * blockDim.x + threadIdx.x;
    int j = gt & 31;
    int g = gt >> 5;
    int ngroups = (gridDim.x * blockDim.x) >> 5;
    for (int q = g; q < novf; q += ngroups) {
        uint2 rec = ovf[q];
        int row = (int)rec.x, col = (int)rec.y;
        float dist = dist_f(pos4[row], pos4[col]);
        uint4 zv = ((const uint4*)(z + (size_t)col * (R * C)))[j];
        float sh = silu_f(rbf_dot(dist, zv, b1[j]));
        float v = 0.f;
#pragma unroll
        for (int i = 0; i < C; ++i)
            v = fmaf(__shfl(sh, i, 32), W2[i * C + j], v);
        atomicAdd(&out[(size_t)row * C + j], v);
    }
}

// rbf for fallback tiers
__device__ __forceinline__ float rbf_lane(float dist, int r) {
    float t = (dist - 0.71428573f * (float)r) * 1.3999999f;
    return 0.3989423f * __expf(-0.5f * t * t);
}

// ---- Tier B kernels (proven fallback) ----
__global__ void k_edge_direct(const int* __restrict__ ei, const float* __restrict__ pos,
                              const float* __restrict__ x, const float* __restrict__ M,
                              const float* __restrict__ b1,
                              float* __restrict__ agg, float* __restrict__ deg,
                              int E, int N) {
    __shared__ float Ms[R * C * C];
    for (int i = threadIdx.x; i < R * C * C; i += blockDim.x) Ms[i] = M[i];
    __syncthreads();
    int gt = blockIdx.x * blockDim.x + threadIdx.x;
    int j = gt & 31;
    int g = gt >> 5;
    int ngroups = (gridDim.x * blockDim.x) >> 5;
    float b1j = b1[j];
    for (int e = g; e < E; e += ngroups) {
        int row = ei[e];
        int col = ei[E + e];
        row = ((unsigned)row < (unsigned)N) ? row : 0;
        col = ((unsigned)col < (unsigned)N) ? col : 0;
        float dx = pos[row * 3 + 0] - pos[col * 3 + 0];
        float dy = pos[row * 3 + 1] - pos[col * 3 + 1];
        float dz = pos[row * 3 + 2] - pos[col * 3 + 2];
        float dist = sqrtf(fmaf(dx, dx, fmaf(dy, dy, dz * dz)) + 1e-12f);
        float my_rbf = rbf_lane(dist, j & 7);
        float xr[C];
#pragma unroll
        for (int c = 0; c < C; ++c) xr[c] = x[(size_t)col * C + c];
        float h = b1j;
#pragma unroll
        for (int r = 0; r < R; ++r) {
            float s = 0.f;
#pragma unroll
            for (int c = 0; c < C; ++c)
                s = fmaf(xr[c], Ms[r * C * C + c * C + j], s);
            h = fmaf(__shfl(my_rbf, r, 32), s, h);
        }
        float sh = h / (1.f + __expf(-h));
        atomicAdd(&agg[(size_t)row * C + j], sh);
        if (j == 0) atomicAdd(&deg[row], 1.f);
    }
}

__global__ void k_final(const float* __restrict__ x, const float* __restrict__ agg,
                        const float* __restrict__ deg, const float* __restrict__ W2,
                        const float* __restrict__ b2, float* __restrict__ out,
                        int N) {
    int t = threadIdx.x;
    int j = t & 31;
    float w2[C];
#pragma unroll
    for (int i = 0; i < C; ++i) w2[i] = W2[i * C + j];
    float b2j = b2[j];
    int g = (blockIdx.x * blockDim.x + t) >> 5;
    int ngroups = (gridDim.x * blockDim.x) >> 5;
    for (int n = g; n < N; n += ngroups) {
        const float* ap = agg + (size_t)n * C;
        float acc = 0.f;
#pragma unroll
        for (int i = 0; i < C; ++i) acc = fmaf(ap[i], w2[i], acc);
        out[(size_t)n * C + j] = x[(size_t)n * C + j] + acc + deg[n] * b2j;
    }
}

// ---- Tier C (no usable ws) ----
__global__ void k_edge_full(const int* __restrict__ ei, const float* __restrict__ pos,
                            const float* __restrict__ x,
                            const float* __restrict__ Wtp, const float* __restrict__ W1,
                            const float* __restrict__ b1,
                            const float* __restrict__ W2, const float* __restrict__ b2,
                            float* __restrict__ out, int E, int N) {
    __shared__ float Ms[R * C * C];
    __shared__ float W2s[C * C];
    for (int idx = threadIdx.x; idx < R * C * C; idx += blockDim.x) {
        int r = idx >> 10, c = (idx >> 5) & 31, jj = idx & 31;
        float acc = 0.f;
#pragma unroll
        for (int o = 0; o < C; ++o)
            acc = fmaf(Wtp[c * R * C + r * C + o], W1[(r * C + o) * C + jj], acc);
        Ms[idx] = acc;
    }
    for (int idx = threadIdx.x; idx < C * C; idx += blockDim.x) W2s[idx] = W2[idx];
    __syncthreads();
    int gt = blockIdx.x * blockDim.x + threadIdx.x;
    int j = gt & 31;
    int g = gt >> 5;
    int ngroups = (gridDim.x * blockDim.x) >> 5;
    float b1j = b1[j];
    float b2j = b2[j];
    for (int e = g; e < E; e += ngroups) {
        int row = ei[e];
        int col = ei[E + e];
        row = ((unsigned)row < (unsigned)N) ? row : 0;
        col = ((unsigned)col < (unsigned)N) ? col : 0;
        float dx = pos[row * 3 + 0] - pos[col * 3 + 0];
        float dy = pos[row * 3 + 1] - pos[col * 3 + 1];
        float dz = pos[row * 3 + 2] - pos[col * 3 + 2];
        float dist = sqrtf(fmaf(dx, dx, fmaf(dy, dy, dz * dz)) + 1e-12f);
        float my_rbf = rbf_lane(dist, j & 7);
        float xr[C];
#pragma unroll
        for (int c = 0; c < C; ++c) xr[c] = x[(size_t)col * C + c];
        float h = b1j;
#pragma unroll
        for (int r = 0; r < R; ++r) {
            float s = 0.f;
#pragma unroll
            for (int c = 0; c < C; ++c)
                s = fmaf(xr[c], Ms[r * C * C + c * C + j], s);
            h = fmaf(__shfl(my_rbf, r, 32), s, h);
        }
        float sh = h / (1.f + __expf(-h));
        float v = b2j;
#pragma unroll
        for (int i = 0; i < C; ++i)
            v = fmaf(__shfl(sh, i, 32), W2s[i * C + j], v);
        atomicAdd(&out[(size_t)row * C + j], v);
    }
}

__global__ void k_add_x(const float* __restrict__ x, float* __restrict__ out, int total) {
    int i = blockIdx.x * blockDim.x + threadIdx.x;
    int stride = gridDim.x * blockDim.x;
    for (; i < total; i += stride) out[i] += x[i];
}

extern "C" void kernel_launch(void* const* d_in, const int* in_sizes, int n_in,
                              void* d_out, int out_size, void* d_ws, size_t ws_size,
                              hipStream_t stream) {
    const float* x   = (const float*)d_in[0];
    const float* pos = (const float*)d_in[1];
    const int*   ei  = (const int*)d_in[2];
    const float* Wtp = (const float*)d_in[3];
    const float* W1  = (const float*)d_in[4];
    const float* b1  = (const float*)d_in[5];
    const float* W2  = (const float*)d_in[6];
    const float* b2  = (const float*)d_in[7];
    int N = in_sizes[0] / C;
    int E = in_sizes[2] / 2;

    char* ws = (char*)d_ws;
    size_t mBytes   = (size_t)R * C * C * sizeof(float);              // 32 KB
    size_t zBytes   = (size_t)N * R * C * sizeof(__hip_bfloat16);     // 25.6 MB
    size_t cntB     = (size_t)N * sizeof(int);                        // 200 KB
    size_t ovfcB    = 64;
    size_t ovfB     = (size_t)OVF_CAP * 8;                            // 0.5 MB
    size_t ellB     = (size_t)N * K_ELL * sizeof(u16);                // 3.2 MB
    size_t pos4B    = (size_t)N * sizeof(float4);                     // 0.8 MB
    size_t aggBytes = (size_t)N * (C + 1) * sizeof(float);            // tier B
    size_t tierANeed = mBytes + zBytes + cntB + ovfcB + ovfB + ellB + pos4B;
    bool tierA = (ws_size >= tierANeed) && (N <= 65535);
    bool tierB = !tierA && ws_size >= mBytes + aggBytes;

    if (tierA) {
        size_t off = 0;
        float*          M      = (float*)(ws + off); off += mBytes;
        __hip_bfloat16* z      = (__hip_bfloat16*)(ws + off); off += zBytes;
        int*            cnt    = (int*)(ws + off); off += cntB;
        int*            ovfcnt = (int*)(ws + off); off += ovfcB;
        uint2*          ovf    = (uint2*)(ws + off); off += ovfB;
        u16*            ell    = (u16*)(ws + off); off += ellB;
        float4*         pos4   = (float4*)(ws + off);

        hipMemsetAsync(cnt, 0, cntB + ovfcB, stream);  // cnt + ovfcnt adjacent
        k_prepM<<<(R * C * C + 255) / 256, 256, 0, stream>>>(Wtp, W1, M);
        int PB = (N + 255) / 256;
        int ZB = (N + NPB - 1) / NPB;
        int SB = (E + 255) / 256;
        k_fused<<<PB + ZB + SB, 256, 0, stream>>>(x, M, z, ei, pos, pos4, cnt,
                                                  ovfcnt, ovf, ell, N, E, PB, ZB);
        int blocks = (int)(((size_t)N * 32 + 255) / 256);
        k_edge_ell<<<blocks, 256, 0, stream>>>(cnt, ell, z, pos4, x, b1, W2, b2,
                                               (float*)d_out, N);
        k_overflow<<<16, 256, 0, stream>>>(ovfcnt, ovf, z, pos4, b1, W2,
                                           (float*)d_out, N);
    } else if (tierB) {
        float* M   = (float*)ws;
        float* agg = (float*)(ws + mBytes);
        float* deg = agg + (size_t)N * C;
        hipMemsetAsync(agg, 0, aggBytes, stream);
        k_prepM<<<(R * C * C + 255) / 256, 256, 0, stream>>>(Wtp, W1, M);
        k_edge_direct<<<2048, 256, 0, stream>>>(ei, pos, x, M, b1, agg, deg, E, N);
        k_final<<<1024, 256, 0, stream>>>(x, agg, deg, W2, b2, (float*)d_out, N);
    } else {
        hipMemsetAsync(d_out, 0, (size_t)N * C * sizeof(float), stream);
        k_edge_full<<<1024, 256, 0, stream>>>(ei, pos, x, Wtp, W1, b1, W2, b2,
                                              (float*)d_out, E, N);
        k_add_x<<<1024, 256, 0, stream>>>(x, (float*)d_out, N * C);
    }
}

// Round 16
// 131.867 us; speedup vs baseline: 1.2368x; 1.2368x over previous
//
#include <hip/hip_runtime.h>
#include <hip/hip_bf16.h>

#define C 32
#define R 8
#define NPB 32        // nodes per block in nodeZ part
#define K_ELL 32      // ELL slots per row
#define OVF_CAP 65536

typedef unsigned int u32;
__device__ __forceinline__ float bflo(u32 u) { return __uint_as_float(u << 16); }
__device__ __forceinline__ float bfhi(u32 u) { return __uint_as_float(u & 0xffff0000u); }
__device__ __forceinline__ u32 f2bf_bits(float f) {
    u32 u = __float_as_uint(f);
    u32 lsb = (u >> 16) & 1u;
    return (u + 0x7fffu + lsb) >> 16;
}

// ---- M[r][c][j] = sum_o W_tp[c][r][o] * W1[r*C+o][j]   (f32, 32 KB) ----
__global__ void k_prepM(const float* __restrict__ Wtp, const float* __restrict__ W1,
                        float* __restrict__ M) {
    int idx = blockIdx.x * 256 + threadIdx.x;
    if (idx >= R * C * C) return;
    int r = idx >> 10;
    int c = (idx >> 5) & 31;
    int j = idx & 31;
    float acc = 0.f;
#pragma unroll
    for (int o = 0; o < C; ++o)
        acc = fmaf(Wtp[c * R * C + r * C + o], W1[(r * C + o) * C + j], acc);
    M[idx] = acc;
}

// ---- fused: blocks [0,ZB): nodeZ | blocks [ZB,..): edge scatter (nt stores) ----
__global__ void k_fused(const float* __restrict__ x, const float* __restrict__ M,
                        __hip_bfloat16* __restrict__ z,
                        const int* __restrict__ ei, const float* __restrict__ pos,
                        int* __restrict__ cnt, int* __restrict__ ovfcnt,
                        uint4* __restrict__ ovf,
                        u32* __restrict__ ell, int N, int E, int ZB) {
    __shared__ float xs[NPB * C];
    int t = threadIdx.x;
    if ((int)blockIdx.x < ZB) {
        int n0 = blockIdx.x * NPB;
        for (int i = t * 4; i < NPB * C; i += 256 * 4) {
            size_t gbase = (size_t)n0 * C + i;
            float4 v = make_float4(0.f, 0.f, 0.f, 0.f);
            if (gbase + 3 < (size_t)N * C) v = *(const float4*)(x + gbase);
            *(float4*)(xs + i) = v;
        }
        __syncthreads();
        int r = t & 7, j = t >> 3;
        float m[C];
#pragma unroll
        for (int c = 0; c < C; ++c) m[c] = M[r * C * C + c * C + j];
        int nmax = N - n0; if (nmax > NPB) nmax = NPB;
        for (int nn = 0; nn < nmax; ++nn) {
            const float* xp = xs + nn * C;
            float acc = 0.f;
#pragma unroll
            for (int c = 0; c < C; ++c) acc = fmaf(xp[c], m[c], acc);
            z[(size_t)(n0 + nn) * (R * C) + t] = __float2bfloat16(acc);
        }
    } else {
        int i = (blockIdx.x - ZB) * 256 + t;
        if (i < E) {
            int r = ei[i];
            int c = ei[E + i];
            r = ((unsigned)r < (unsigned)N) ? r : 0;
            c = ((unsigned)c < (unsigned)N) ? c : 0;
            float dx = pos[r * 3 + 0] - pos[c * 3 + 0];
            float dy = pos[r * 3 + 1] - pos[c * 3 + 1];
            float dz = pos[r * 3 + 2] - pos[c * 3 + 2];
            float dist = sqrtf(fmaf(dx, dx, fmaf(dy, dy, dz * dz)) + 1e-12f);
            int local = atomicAdd(&cnt[r], 1);
            if (local < K_ELL) {
                u32 pack = (u32)c | (f2bf_bits(dist) << 16);
                // non-temporal: no L2 dirty-line allocation -> no cross-XCD churn
                __builtin_nontemporal_store(pack, &ell[(size_t)r * K_ELL + local]);
            } else {
                int q = atomicAdd(ovfcnt, 1);
                if (q < OVF_CAP)
                    ovf[q] = make_uint4((u32)r, (u32)c, __float_as_uint(dist), 0u);
            }
        }
    }
}

__device__ __forceinline__ float silu_f(float h) {
    return h * __builtin_amdgcn_rcpf(1.f + __expf(-h));
}

// per-lane full-rbf dot: h = b1j + sum_r rbf(d,r)*z_r  — 2 exps, no shuffles.
// rbf[r] = s*exp(-0.5(u-r)^2), u=d/w, w=5/7:  f_{r+1}=f_r*m_r, m_0=exp(u-1/2),
// m_{r+1}=m_r*e^-1.
__device__ __forceinline__ float rbf_dot(float d, uint4 zv, float b1j) {
    const float Einv = 0.36787944f;   // e^-1
    float u = 1.3999999f * d;
    float f = 0.3989423f * __expf(-0.5f * u * u);
    float t = __expf(u - 0.5f);
    float h = fmaf(f, bflo(zv.x), b1j);
    f *= t;            h = fmaf(f, bfhi(zv.x), h);
    t *= Einv; f *= t; h = fmaf(f, bflo(zv.y), h);
    t *= Einv; f *= t; h = fmaf(f, bfhi(zv.y), h);
    t *= Einv; f *= t; h = fmaf(f, bflo(zv.z), h);
    t *= Einv; f *= t; h = fmaf(f, bfhi(zv.z), h);
    t *= Einv; f *= t; h = fmaf(f, bflo(zv.w), h);
    t *= Einv; f *= t; h = fmaf(f, bfhi(zv.w), h);
    return h;
}

// ---- per-row ELL edge kernel: 32 lanes = one row; fused W2/b2 epilogue ----
__global__ void k_edge_ell(const int* __restrict__ cnt, const u32* __restrict__ ell,
                           const __hip_bfloat16* __restrict__ z,
                           const float* __restrict__ x, const float* __restrict__ b1,
                           const float* __restrict__ W2, const float* __restrict__ b2,
                           float* __restrict__ out, int N) {
    __shared__ float W2s[C * C];
    for (int i = threadIdx.x; i < C * C; i += blockDim.x) W2s[i] = W2[i];
    __syncthreads();
    int gt = blockIdx.x * blockDim.x + threadIdx.x;
    int j = gt & 31;
    int n = gt >> 5;
    if (n >= N) return;
    int deg = cnt[n];
    int m = deg < K_ELL ? deg : K_ELL;
    u32 packv = 0u;
    if (j < m) packv = ell[(size_t)n * K_ELL + j];
    float b1j = b1[j];
    float acc = 0.f;
    int base = 0;
    for (; base + 4 <= m; base += 4) {
        u32 w0 = __shfl(packv, base + 0, 32);
        u32 w1 = __shfl(packv, base + 1, 32);
        u32 w2 = __shfl(packv, base + 2, 32);
        u32 w3 = __shfl(packv, base + 3, 32);
        uint4 z0 = ((const uint4*)(z + (size_t)(w0 & 0xffffu) * (R * C)))[j];
        uint4 z1 = ((const uint4*)(z + (size_t)(w1 & 0xffffu) * (R * C)))[j];
        uint4 z2 = ((const uint4*)(z + (size_t)(w2 & 0xffffu) * (R * C)))[j];
        uint4 z3 = ((const uint4*)(z + (size_t)(w3 & 0xffffu) * (R * C)))[j];
        float h0 = rbf_dot(__uint_as_float(w0 & 0xffff0000u), z0, b1j);
        float h1 = rbf_dot(__uint_as_float(w1 & 0xffff0000u), z1, b1j);
        float h2 = rbf_dot(__uint_as_float(w2 & 0xffff0000u), z2, b1j);
        float h3 = rbf_dot(__uint_as_float(w3 & 0xffff0000u), z3, b1j);
        acc += silu_f(h0) + silu_f(h1) + silu_f(h2) + silu_f(h3);
    }
    for (; base < m; ++base) {
        u32 w0 = __shfl(packv, base, 32);
        uint4 z0 = ((const uint4*)(z + (size_t)(w0 & 0xffffu) * (R * C)))[j];
        acc += silu_f(rbf_dot(__uint_as_float(w0 & 0xffff0000u), z0, b1j));
    }
    // out[n][j] = x[n][j] + sum_i acc_i*W2[i][j] + deg*b2[j]   (deg = TRUE degree)
    float v = fmaf((float)deg, b2[j], x[(size_t)n * C + j]);
#pragma unroll
    for (int i = 0; i < C; ++i)
        v = fmaf(__shfl(acc, i, 32), W2s[i * C + j], v);
    out[(size_t)n * C + j] = v;
}

// ---- overflow fix-up: add W2-weighted silu of overflow edges (b2 already counted) ----
__global__ void k_overflow(const int* __restrict__ ovfcnt, const uint4* __restrict__ ovf,
                           const __hip_bfloat16* __restrict__ z,
                           const float* __restrict__ b1, const float* __restrict__ W2,
                           float* __restrict__ out, int N) {
    int novf = ovfcnt[0];
    if (novf > OVF_CAP) novf = OVF_CAP;
    int gt = blockIdx.x * blockDim.x + threadIdx.x;
    int j = gt & 31;
    int g = gt >> 5;
    int ngroups = (gridDim.x * blockDim.x) >> 5;
    for (int q = g; q < novf; q += ngroups) {
        uint4 rec = ovf[q];
        u32 row = rec.x, col = rec.y;
        float dist = __uint_as_float(rec.z);
        uint4 zv = ((const uint4*)(z + (size_t)col * (R * C)))[j];
        float sh = silu_f(rbf_dot(dist, zv, b1[j]));
        float v = 0.f;
#pragma unroll
        for (int i = 0; i < C; ++i)
            v = fmaf(__shfl(sh, i, 32), W2[i * C + j], v);
        atomicAdd(&out[(size_t)row * C + j], v);
    }
}

// rbf for fallback tiers
__device__ __forceinline__ float rbf_lane(float dist, int r) {
    float t = (dist - 0.71428573f * (float)r) * 1.3999999f;
    return 0.3989423f * __expf(-0.5f * t * t);
}

// ---- Tier B kernels (proven fallback) ----
__global__ void k_edge_direct(const int* __restrict__ ei, const float* __restrict__ pos,
                              const float* __restrict__ x, const float* __restrict__ M,
                              const float* __restrict__ b1,
                              float* __restrict__ agg, float* __restrict__ deg,
                              int E, int N) {
    __shared__ float Ms[R * C * C];
    for (int i = threadIdx.x; i < R * C * C; i += blockDim.x) Ms[i] = M[i];
    __syncthreads();
    int gt = blockIdx.x * blockDim.x + threadIdx.x;
    int j = gt & 31;
    int g = gt >> 5;
    int ngroups = (gridDim.x * blockDim.x) >> 5;
    float b1j = b1[j];
    for (int e = g; e < E; e += ngroups) {
        int row = ei[e];
        int col = ei[E + e];
        row = ((unsigned)row < (unsigned)N) ? row : 0;
        col = ((unsigned)col < (unsigned)N) ? col : 0;
        float dx = pos[row * 3 + 0] - pos[col * 3 + 0];
        float dy = pos[row * 3 + 1] - pos[col * 3 + 1];
        float dz = pos[row * 3 + 2] - pos[col * 3 + 2];
        float dist = sqrtf(fmaf(dx, dx, fmaf(dy, dy, dz * dz)) + 1e-12f);
        float my_rbf = rbf_lane(dist, j & 7);
        float xr[C];
#pragma unroll
        for (int c = 0; c < C; ++c) xr[c] = x[(size_t)col * C + c];
        float h = b1j;
#pragma unroll
        for (int r = 0; r < R; ++r) {
            float s = 0.f;
#pragma unroll
            for (int c = 0; c < C; ++c)
                s = fmaf(xr[c], Ms[r * C * C + c * C + j], s);
            h = fmaf(__shfl(my_rbf, r, 32), s, h);
        }
        float sh = h / (1.f + __expf(-h));
        atomicAdd(&agg[(size_t)row * C + j], sh);
        if (j == 0) atomicAdd(&deg[row], 1.f);
    }
}

__global__ void k_final(const float* __restrict__ x, const float* __restrict__ agg,
                        const float* __restrict__ deg, const float* __restrict__ W2,
                        const float* __restrict__ b2, float* __restrict__ out,
                        int N) {
    int t = threadIdx.x;
    int j = t & 31;
    float w2[C];
#pragma unroll
    for (int i = 0; i < C; ++i) w2[i] = W2[i * C + j];
    float b2j = b2[j];
    int g = (blockIdx.x * blockDim.x + t) >> 5;
    int ngroups = (gridDim.x * blockDim.x) >> 5;
    for (int n = g; n < N; n += ngroups) {
        const float* ap = agg + (size_t)n * C;
        float acc = 0.f;
#pragma unroll
        for (int i = 0; i < C; ++i) acc = fmaf(ap[i], w2[i], acc);
        out[(size_t)n * C + j] = x[(size_t)n * C + j] + acc + deg[n] * b2j;
    }
}

// ---- Tier C (no usable ws) ----
__global__ void k_edge_full(const int* __restrict__ ei, const float* __restrict__ pos,
                            const float* __restrict__ x,
                            const float* __restrict__ Wtp, const float* __restrict__ W1,
                            const float* __restrict__ b1,
                            const float* __restrict__ W2, const float* __restrict__ b2,
                            float* __restrict__ out, int E, int N) {
    __shared__ float Ms[R * C * C];
    __shared__ float W2s[C * C];
    for (int idx = threadIdx.x; idx < R * C * C; idx += blockDim.x) {
        int r = idx >> 10, c = (idx >> 5) & 31, jj = idx & 31;
        float acc = 0.f;
#pragma unroll
        for (int o = 0; o < C; ++o)
            acc = fmaf(Wtp[c * R * C + r * C + o], W1[(r * C + o) * C + jj], acc);
        Ms[idx] = acc;
    }
    for (int idx = threadIdx.x; idx < C * C; idx += blockDim.x) W2s[idx] = W2[idx];
    __syncthreads();
    int gt = blockIdx.x * blockDim.x + threadIdx.x;
    int j = gt & 31;
    int g = gt >> 5;
    int ngroups = (gridDim.x * blockDim.x) >> 5;
    float b1j = b1[j];
    float b2j = b2[j];
    for (int e = g; e < E; e += ngroups) {
        int row = ei[e];
        int col = ei[E + e];
        row = ((unsigned)row < (unsigned)N) ? row : 0;
        col = ((unsigned)col < (unsigned)N) ? col : 0;
        float dx = pos[row * 3 + 0] - pos[col * 3 + 0];
        float dy = pos[row * 3 + 1] - pos[col * 3 + 1];
        float dz = pos[row * 3 + 2] - pos[col * 3 + 2];
        float dist = sqrtf(fmaf(dx, dx, fmaf(dy, dy, dz * dz)) + 1e-12f);
        float my_rbf = rbf_lane(dist, j & 7);
        float xr[C];
#pragma unroll
        for (int c = 0; c < C; ++c) xr[c] = x[(size_t)col * C + c];
        float h = b1j;
#pragma unroll
        for (int r = 0; r < R; ++r) {
            float s = 0.f;
#pragma unroll
            for (int c = 0; c < C; ++c)
                s = fmaf(xr[c], Ms[r * C * C + c * C + j], s);
            h = fmaf(__shfl(my_rbf, r, 32), s, h);
        }
        float sh = h / (1.f + __expf(-h));
        float v = b2j;
#pragma unroll
        for (int i = 0; i < C; ++i)
            v = fmaf(__shfl(sh, i, 32), W2s[i * C + j], v);
        atomicAdd(&out[(size_t)row * C + j], v);
    }
}

__global__ void k_add_x(const float* __restrict__ x, float* __restrict__ out, int total) {
    int i = blockIdx.x * blockDim.x + threadIdx.x;
    int stride = gridDim.x * blockDim.x;
    for (; i < total; i += stride) out[i] += x[i];
}

extern "C" void kernel_launch(void* const* d_in, const int* in_sizes, int n_in,
                              void* d_out, int out_size, void* d_ws, size_t ws_size,
                              hipStream_t stream) {
    const float* x   = (const float*)d_in[0];
    const float* pos = (const float*)d_in[1];
    const int*   ei  = (const int*)d_in[2];
    const float* Wtp = (const float*)d_in[3];
    const float* W1  = (const float*)d_in[4];
    const float* b1  = (const float*)d_in[5];
    const float* W2  = (const float*)d_in[6];
    const float* b2  = (const float*)d_in[7];
    int N = in_sizes[0] / C;
    int E = in_sizes[2] / 2;

    char* ws = (char*)d_ws;
    size_t mBytes   = (size_t)R * C * C * sizeof(float);              // 32 KB
    size_t zBytes   = (size_t)N * R * C * sizeof(__hip_bfloat16);     // 25.6 MB
    size_t cntB     = (size_t)N * sizeof(int);                        // 200 KB
    size_t ovfcB    = 64;
    size_t ovfB     = (size_t)OVF_CAP * 16;                           // 1 MB
    size_t ellB     = (size_t)N * K_ELL * sizeof(u32);                // 6.4 MB
    size_t aggBytes = (size_t)N * (C + 1) * sizeof(float);            // tier B
    size_t tierANeed = mBytes + zBytes + cntB + ovfcB + ovfB + ellB;
    bool tierA = (ws_size >= tierANeed) && (N <= 65535);
    bool tierB = !tierA && ws_size >= mBytes + aggBytes;

    if (tierA) {
        size_t off = 0;
        float*          M      = (float*)(ws + off); off += mBytes;
        __hip_bfloat16* z      = (__hip_bfloat16*)(ws + off); off += zBytes;
        int*            cnt    = (int*)(ws + off); off += cntB;
        int*            ovfcnt = (int*)(ws + off); off += ovfcB;
        uint4*          ovf    = (uint4*)(ws + off); off += ovfB;
        u32*            ell    = (u32*)(ws + off);

        hipMemsetAsync(cnt, 0, cntB + ovfcB, stream);  // cnt + ovfcnt adjacent
        k_prepM<<<(R * C * C + 255) / 256, 256, 0, stream>>>(Wtp, W1, M);
        int ZB = (N + NPB - 1) / NPB;
        int SB = (E + 255) / 256;
        k_fused<<<ZB + SB, 256, 0, stream>>>(x, M, z, ei, pos, cnt, ovfcnt, ovf,
                                             ell, N, E, ZB);
        int blocks = (int)(((size_t)N * 32 + 255) / 256);
        k_edge_ell<<<blocks, 256, 0, stream>>>(cnt, ell, z, x, b1, W2, b2,
                                               (float*)d_out, N);
        k_overflow<<<16, 256, 0, stream>>>(ovfcnt, ovf, z, b1, W2,
                                           (float*)d_out, N);
    } else if (tierB) {
        float* M   = (float*)ws;
        float* agg = (float*)(ws + mBytes);
        float* deg = agg + (size_t)N * C;
        hipMemsetAsync(agg, 0, aggBytes, stream);
        k_prepM<<<(R * C * C + 255) / 256, 256, 0, stream>>>(Wtp, W1, M);
        k_edge_direct<<<2048, 256, 0, stream>>>(ei, pos, x, M, b1, agg, deg, E, N);
        k_final<<<1024, 256, 0, stream>>>(x, agg, deg, W2, b2, (float*)d_out, N);
    } else {
        hipMemsetAsync(d_out, 0, (size_t)N * C * sizeof(float), stream);
        k_edge_full<<<1024, 256, 0, stream>>>(ei, pos, x, Wtp, W1, b1, W2, b2,
                                              (float*)d_out, E, N);
        k_add_x<<<1024, 256, 0, stream>>>(x, (float*)d_out, N * C);
    }
}